// Round 1
// baseline (305.821 us; speedup 1.0000x reference)
//
#include <hip/hip_runtime.h>
#include <hip/hip_bf16.h>
#include <stdint.h>

// BertAttention (feature-axis attention):
//   q = x@Wq^T+bq; k = x@Wk^T+bk; v = x@Wv^T+bv        [S,D]
//   scores = (q^T k)/sqrt(D)  -> [D,D]; attn = softmax(scores, axis=-1)
//   out = v @ attn  [S,D];  outputs: (out fp32 [S,D], attn fp32 [D,D])
// Strategy: fp16 MFMA (16x16x32) everywhere, fp32 accum. All GEMMs in
// A·B^T (both K-contiguous) form; qT/kT produced transposed by operand swap.

#define S_ 16384
#define D_ 1024

typedef _Float16 half8 __attribute__((ext_vector_type(8)));
typedef float f32x4 __attribute__((ext_vector_type(4)));

__device__ __forceinline__ void gload_lds16(const _Float16* g, _Float16* l) {
    __builtin_amdgcn_global_load_lds(
        (const __attribute__((address_space(1))) void*)g,
        (__attribute__((address_space(3))) void*)l, 16, 0, 0);
}

// C[m,n] = scale * sum_k A[m,k]*B[n,k] (+bias). 128x128 tile, 4 waves,
// BK=32, global_load_lds staging, m97 2-barrier structure.
template <int F16OUT>
__global__ __launch_bounds__(256, 2)
void gemm_abt(const _Float16* __restrict__ A, const _Float16* __restrict__ B,
              void* __restrict__ C, const float* __restrict__ bias,
              int bias_mode, int lda, int ldb, int ldc, int ksub,
              float scale, long long mn) {
    const int t = threadIdx.x;
    const int lane = t & 63;
    const int wave = t >> 6;
    const int wr = (wave >> 1) * 64;
    const int wc = (wave & 1) * 64;
    const size_t m0 = (size_t)blockIdx.y * 128;
    const size_t n0 = (size_t)blockIdx.x * 128;
    const size_t k0 = (size_t)blockIdx.z * (size_t)ksub;
    const long long coff = (long long)blockIdx.z * mn;

    __shared__ _Float16 As[128 * 32];
    __shared__ _Float16 Bs[128 * 32];

    f32x4 acc[4][4] = {};

    // staging: 512 16B-chunks per tile; thread t handles chunks t and t+256.
    // chunk f: row = f>>2, elem-col = (f&3)*8  (tile is [128][32] f16 row-major)
    const _Float16* a0 = A + (m0 + (size_t)(t >> 2)) * (size_t)lda + k0 + (t & 3) * 8;
    const _Float16* a1 = a0 + (size_t)64 * lda;
    const _Float16* b0 = B + (n0 + (size_t)(t >> 2)) * (size_t)ldb + k0 + (t & 3) * 8;
    const _Float16* b1 = b0 + (size_t)64 * ldb;
    _Float16* AsW0 = As + wave * 512;         // chunks [wave*64, wave*64+64)
    _Float16* AsW1 = As + 2048 + wave * 512;  // chunks [256+wave*64, ...)
    _Float16* BsW0 = Bs + wave * 512;
    _Float16* BsW1 = Bs + 2048 + wave * 512;

    const int nk = ksub >> 5;
    for (int kt = 0; kt < nk; ++kt) {
        __syncthreads();  // previous compute done before overwrite
        gload_lds16(a0, AsW0);
        gload_lds16(a1, AsW1);
        gload_lds16(b0, BsW0);
        gload_lds16(b1, BsW1);
        a0 += 32; a1 += 32; b0 += 32; b1 += 32;
        __syncthreads();  // vmcnt(0) drained by barrier -> tiles visible

        half8 af[4], bf[4];
#pragma unroll
        for (int i = 0; i < 4; ++i)
            af[i] = *(const half8*)(As + (wr + i * 16 + (lane & 15)) * 32 + (lane >> 4) * 8);
#pragma unroll
        for (int i = 0; i < 4; ++i)
            bf[i] = *(const half8*)(Bs + (wc + i * 16 + (lane & 15)) * 32 + (lane >> 4) * 8);
#pragma unroll
        for (int i = 0; i < 4; ++i)
#pragma unroll
            for (int j = 0; j < 4; ++j)
                acc[i][j] = __builtin_amdgcn_mfma_f32_16x16x32_f16(af[i], bf[j], acc[i][j], 0, 0, 0);
    }

    // epilogue: C/D layout col=lane&15, row=(lane>>4)*4+r  (m89-verified)
    const int cr = (lane >> 4) * 4;
    const int cc = lane & 15;
#pragma unroll
    for (int i = 0; i < 4; ++i) {
#pragma unroll
        for (int j = 0; j < 4; ++j) {
            const size_t row0 = m0 + wr + i * 16 + cr;
            const size_t col = n0 + wc + j * 16 + cc;
            const float bcol = (bias_mode == 2) ? bias[col] : 0.f;
#pragma unroll
            for (int r = 0; r < 4; ++r) {
                float val = acc[i][j][r] * scale;
                if (bias_mode == 1) val += bias[row0 + r];
                val += bcol;
                if (F16OUT)
                    ((_Float16*)C)[(row0 + r) * (size_t)ldc + col] = (_Float16)val;
                else
                    ((float*)C)[coff + (long long)(row0 + r) * ldc + col] = val;
            }
        }
    }
}

__global__ void cast_f32_f16(const float* __restrict__ in, _Float16* __restrict__ out, int n8) {
    int i = blockIdx.x * 256 + threadIdx.x;
    if (i >= n8) return;
    const f32x4* p = (const f32x4*)in + (size_t)i * 2;
    f32x4 x0 = p[0], x1 = p[1];
    half8 h;
    h[0] = (_Float16)x0[0]; h[1] = (_Float16)x0[1];
    h[2] = (_Float16)x0[2]; h[3] = (_Float16)x0[3];
    h[4] = (_Float16)x1[0]; h[5] = (_Float16)x1[1];
    h[6] = (_Float16)x1[2]; h[7] = (_Float16)x1[3];
    ((half8*)out)[i] = h;
}

// one block per row a: reduce 8 split-K partials, softmax over 1024 cols,
// write attn fp32 (d_out) + attn^T fp16 (for out-GEMM B operand).
__global__ __launch_bounds__(256)
void softmax_rows(const float* __restrict__ part, float* __restrict__ P,
                  _Float16* __restrict__ PT) {
    const int a = blockIdx.x;
    const int t = threadIdx.x;
    __shared__ float red[8];
    const size_t off = (size_t)a * 1024 + t * 4;
    f32x4 s = {};
#pragma unroll
    for (int z = 0; z < 8; ++z)
        s += *(const f32x4*)(part + (size_t)z * 1048576 + off);

    float m = fmaxf(fmaxf(s[0], s[1]), fmaxf(s[2], s[3]));
    for (int o = 32; o; o >>= 1) m = fmaxf(m, __shfl_xor(m, o));
    if ((t & 63) == 0) red[t >> 6] = m;
    __syncthreads();
    m = fmaxf(fmaxf(red[0], red[1]), fmaxf(red[2], red[3]));

    float e0 = expf(s[0] - m), e1 = expf(s[1] - m);
    float e2 = expf(s[2] - m), e3 = expf(s[3] - m);
    float sum = e0 + e1 + e2 + e3;
    for (int o = 32; o; o >>= 1) sum += __shfl_xor(sum, o);
    if ((t & 63) == 0) red[4 + (t >> 6)] = sum;
    __syncthreads();
    sum = red[4] + red[5] + red[6] + red[7];
    const float inv = 1.0f / sum;

    f32x4 o4 = {e0 * inv, e1 * inv, e2 * inv, e3 * inv};
    *(f32x4*)(P + off) = o4;
    const int b = t * 4;
    PT[(size_t)(b + 0) * 1024 + a] = (_Float16)o4[0];
    PT[(size_t)(b + 1) * 1024 + a] = (_Float16)o4[1];
    PT[(size_t)(b + 2) * 1024 + a] = (_Float16)o4[2];
    PT[(size_t)(b + 3) * 1024 + a] = (_Float16)o4[3];
}

extern "C" void kernel_launch(void* const* d_in, const int* in_sizes, int n_in,
                              void* d_out, int out_size, void* d_ws, size_t ws_size,
                              hipStream_t stream) {
    const float* x  = (const float*)d_in[0];
    const float* Wq = (const float*)d_in[1];
    const float* bq = (const float*)d_in[2];
    const float* Wk = (const float*)d_in[3];
    const float* bk = (const float*)d_in[4];
    const float* Wv = (const float*)d_in[5];
    const float* bv = (const float*)d_in[6];
    float* out  = (float*)d_out;                     // [S,D] fp32
    float* attn = out + (size_t)S_ * D_;             // [D,D] fp32

    char* ws = (char*)d_ws;
    // layout (bytes):
    _Float16* x16  = (_Float16*)ws;                        // 33.5MB (reused as partials)
    float*    part = (float*)ws;                           // alias: after GEMM1 done
    _Float16* wq16 = (_Float16*)(ws + 33554432);           // 2MB (reused as PT)
    _Float16* PT   = wq16;                                 // alias: after gemm-q done
    _Float16* wk16 = (_Float16*)(ws + 35651584);
    _Float16* wv16 = (_Float16*)(ws + 37748736);
    _Float16* qT   = (_Float16*)(ws + 39845888);           // [D,S] 33.5MB
    _Float16* kT   = (_Float16*)(ws + 73400320);           // [D,S] 33.5MB
    _Float16* v16  = (_Float16*)(ws + 106954752);          // [S,D] 33.5MB

    // casts to fp16
    cast_f32_f16<<<8192, 256, 0, stream>>>(x,  x16,  S_ * D_ / 8);
    cast_f32_f16<<<512,  256, 0, stream>>>(Wq, wq16, D_ * D_ / 8);
    cast_f32_f16<<<512,  256, 0, stream>>>(Wk, wk16, D_ * D_ / 8);
    cast_f32_f16<<<512,  256, 0, stream>>>(Wv, wv16, D_ * D_ / 8);

    // qT[d,s] = sum_i Wq[d,i] x[s,i] + bq[d]   (M=1024, N=16384, K=1024)
    gemm_abt<1><<<dim3(128, 8, 1), 256, 0, stream>>>(wq16, x16, qT, bq, 1,
                                                     1024, 1024, 16384, 1024, 1.0f, 0);
    // kT
    gemm_abt<1><<<dim3(128, 8, 1), 256, 0, stream>>>(wk16, x16, kT, bk, 1,
                                                     1024, 1024, 16384, 1024, 1.0f, 0);
    // v[s,a] = sum_i x[s,i] Wv[a,i] + bv[a]    (M=16384, N=1024, K=1024)
    gemm_abt<1><<<dim3(8, 128, 1), 256, 0, stream>>>(x16, wv16, v16, bv, 2,
                                                     1024, 1024, 1024, 1024, 1.0f, 0);
    // scores partials: part[z][a][b] = (1/32) sum_{k in z} qT[a,k] kT[b,k]
    // (M=N=1024, K=16384 split 8)  -- part aliases x16 (x16 dead now)
    gemm_abt<0><<<dim3(8, 8, 8), 256, 0, stream>>>(qT, kT, part, nullptr, 0,
                                                   16384, 16384, 1024, 2048,
                                                   0.03125f, 1048576);
    // softmax -> attn (fp32, d_out) + PT (fp16) ; PT aliases wq16 (dead now)
    softmax_rows<<<1024, 256, 0, stream>>>(part, attn, PT);
    // out[s,j] = sum_a v[s,a] PT[j,a]          (M=16384, N=1024, K=1024)
    gemm_abt<0><<<dim3(8, 128, 1), 256, 0, stream>>>(v16, PT, out, nullptr, 0,
                                                     1024, 1024, 1024, 1024, 1.0f, 0);
}

// Round 2
// 226.307 us; speedup vs baseline: 1.3514x; 1.3514x over previous
//
#include <hip/hip_runtime.h>
#include <hip/hip_bf16.h>
#include <stdint.h>

// BertAttention (feature-axis attention), algebraically restructured:
//   G = x^T x  [D,D];  m = colsum(x);  u2 = Wq m + S*bq;  w = Wk m
//   scores = (Wq G Wk^T + u2 bk^T + bq w^T)/sqrt(D); attn = softmax(scores)
//   out = x (Wv^T attn) + 1 (bv^T attn)
// => only two S-sized GEMMs (G and out), three 1024^3 GEMMs, rank-1 epilogues.
// All GEMMs fp16 MFMA (16x16x32), fp32 accumulate.

#define S_ 16384
#define D_ 1024

typedef _Float16 half8 __attribute__((ext_vector_type(8)));
typedef _Float16 half4 __attribute__((ext_vector_type(4)));
typedef float f32x4 __attribute__((ext_vector_type(4)));

__device__ __forceinline__ void gload_lds16(const _Float16* g, _Float16* l) {
    __builtin_amdgcn_global_load_lds(
        (const __attribute__((address_space(1))) void*)g,
        (__attribute__((address_space(3))) void*)l, 16, 0, 0);
}

// C[m,n] = scale * sum_k A[m,k]*B[n,k] (+bias). 128x128 tile, 4 waves,
// BK=32, global_load_lds staging, 2-barrier structure. fp32 output with
// split-K partial offset coff = blockIdx.z * mn.
__global__ __launch_bounds__(256, 2)
void gemm_abt(const _Float16* __restrict__ A, const _Float16* __restrict__ B,
              float* __restrict__ C, const float* __restrict__ bias,
              int bias_mode, int lda, int ldb, int ldc, int ksub,
              float scale, long long mn) {
    const int t = threadIdx.x;
    const int lane = t & 63;
    const int wave = t >> 6;
    const int wr = (wave >> 1) * 64;
    const int wc = (wave & 1) * 64;
    const size_t m0 = (size_t)blockIdx.y * 128;
    const size_t n0 = (size_t)blockIdx.x * 128;
    const size_t k0 = (size_t)blockIdx.z * (size_t)ksub;
    const long long coff = (long long)blockIdx.z * mn;

    __shared__ _Float16 As[128 * 32];
    __shared__ _Float16 Bs[128 * 32];

    f32x4 acc[4][4] = {};

    const _Float16* a0 = A + (m0 + (size_t)(t >> 2)) * (size_t)lda + k0 + (t & 3) * 8;
    const _Float16* a1 = a0 + (size_t)64 * lda;
    const _Float16* b0 = B + (n0 + (size_t)(t >> 2)) * (size_t)ldb + k0 + (t & 3) * 8;
    const _Float16* b1 = b0 + (size_t)64 * ldb;
    _Float16* AsW0 = As + wave * 512;
    _Float16* AsW1 = As + 2048 + wave * 512;
    _Float16* BsW0 = Bs + wave * 512;
    _Float16* BsW1 = Bs + 2048 + wave * 512;

    const int nk = ksub >> 5;
    for (int kt = 0; kt < nk; ++kt) {
        __syncthreads();
        gload_lds16(a0, AsW0);
        gload_lds16(a1, AsW1);
        gload_lds16(b0, BsW0);
        gload_lds16(b1, BsW1);
        a0 += 32; a1 += 32; b0 += 32; b1 += 32;
        __syncthreads();

        half8 af[4], bf[4];
#pragma unroll
        for (int i = 0; i < 4; ++i)
            af[i] = *(const half8*)(As + (wr + i * 16 + (lane & 15)) * 32 + (lane >> 4) * 8);
#pragma unroll
        for (int i = 0; i < 4; ++i)
            bf[i] = *(const half8*)(Bs + (wc + i * 16 + (lane & 15)) * 32 + (lane >> 4) * 8);
#pragma unroll
        for (int i = 0; i < 4; ++i)
#pragma unroll
            for (int j = 0; j < 4; ++j)
                acc[i][j] = __builtin_amdgcn_mfma_f32_16x16x32_f16(af[i], bf[j], acc[i][j], 0, 0, 0);
    }

    const int cr = (lane >> 4) * 4;
    const int cc = lane & 15;
#pragma unroll
    for (int i = 0; i < 4; ++i) {
#pragma unroll
        for (int j = 0; j < 4; ++j) {
            const size_t row0 = m0 + wr + i * 16 + cr;
            const size_t col = n0 + wc + j * 16 + cc;
            const float bcol = (bias_mode == 2) ? bias[col] : 0.f;
#pragma unroll
            for (int r = 0; r < 4; ++r) {
                float val = acc[i][j][r] * scale + bcol;
                C[coff + (long long)(row0 + r) * ldc + col] = val;
            }
        }
    }
}

// fp32 -> fp16 cast (8 elems/thread)
__global__ void cast_f32_f16(const float* __restrict__ in, _Float16* __restrict__ out, int n8) {
    int i = blockIdx.x * 256 + threadIdx.x;
    if (i >= n8) return;
    const f32x4* p = (const f32x4*)in + (size_t)i * 2;
    f32x4 x0 = p[0], x1 = p[1];
    half8 h;
    h[0] = (_Float16)x0[0]; h[1] = (_Float16)x0[1];
    h[2] = (_Float16)x0[2]; h[3] = (_Float16)x0[3];
    h[4] = (_Float16)x1[0]; h[5] = (_Float16)x1[1];
    h[6] = (_Float16)x1[2]; h[7] = (_Float16)x1[3];
    ((half8*)out)[i] = h;
}

// 64x64 tile: in [R][1024] f32 -> outT [1024][ldT] f16 (+ optional row-major
// f16 copy and fp32 column-sum atomics).
template <int WRITE_ROW, int COLSUM>
__global__ __launch_bounds__(256)
void cast_transpose(const float* __restrict__ in, _Float16* __restrict__ outRow,
                    _Float16* __restrict__ outT, float* __restrict__ msum, int ldT) {
    __shared__ _Float16 tile[64][66];
    __shared__ float red[16][16][4];
    const int t = threadIdx.x;
    const int c0 = blockIdx.x * 64;
    const int r0 = blockIdx.y * 64;
    const int cg = t & 15;
    const int rb = t >> 4;
    f32x4 csum = {};
#pragma unroll
    for (int it = 0; it < 4; ++it) {
        const int rr = rb + it * 16;
        f32x4 v = *(const f32x4*)(in + (size_t)(r0 + rr) * 1024 + c0 + cg * 4);
        if (COLSUM) { csum[0] += v[0]; csum[1] += v[1]; csum[2] += v[2]; csum[3] += v[3]; }
        _Float16 h0 = (_Float16)v[0], h1 = (_Float16)v[1];
        _Float16 h2 = (_Float16)v[2], h3 = (_Float16)v[3];
        tile[rr][cg * 4 + 0] = h0; tile[rr][cg * 4 + 1] = h1;
        tile[rr][cg * 4 + 2] = h2; tile[rr][cg * 4 + 3] = h3;
        if (WRITE_ROW) {
            half4 h = {h0, h1, h2, h3};
            *(half4*)(outRow + (size_t)(r0 + rr) * 1024 + c0 + cg * 4) = h;
        }
    }
    if (COLSUM) {
        red[rb][cg][0] = csum[0]; red[rb][cg][1] = csum[1];
        red[rb][cg][2] = csum[2]; red[rb][cg][3] = csum[3];
    }
    __syncthreads();
    if (COLSUM && t < 64) {
        float s = 0.f;
#pragma unroll
        for (int k = 0; k < 16; ++k) s += red[k][t >> 2][t & 3];
        atomicAdd(msum + c0 + t, s);
    }
    const int i = t >> 2, ch = (t & 3) * 16;
    half8 h0v, h1v;
#pragma unroll
    for (int j = 0; j < 8; ++j) h0v[j] = tile[ch + j][i];
#pragma unroll
    for (int j = 0; j < 8; ++j) h1v[j] = tile[ch + 8 + j][i];
    *(half8*)(outT + (size_t)(c0 + i) * ldT + r0 + ch) = h0v;
    *(half8*)(outT + (size_t)(c0 + i) * ldT + r0 + ch + 8) = h1v;
}

__global__ void zero_vec(float* __restrict__ p, int n) {
    int i = blockIdx.x * 256 + threadIdx.x;
    if (i < n) p[i] = 0.f;
}

// u2[a] = sum_i Wq[a,i] m[i] + S*bq[a];  w[b] = sum_i Wk[b,i] m[i]
__global__ __launch_bounds__(256)
void u2w_kernel(const float* __restrict__ Wq, const float* __restrict__ Wk,
                const float* __restrict__ bq, const float* __restrict__ m,
                float* __restrict__ u2, float* __restrict__ w) {
    const int bid = blockIdx.x;
    const int t = threadIdx.x;
    const float* W = (bid < 1024) ? Wq : Wk;
    const int row = (bid < 1024) ? bid : bid - 1024;
    float s = 0.f;
#pragma unroll
    for (int it = 0; it < 4; ++it) {
        const int i = t + it * 256;
        s += W[(size_t)row * 1024 + i] * m[i];
    }
    for (int o = 32; o; o >>= 1) s += __shfl_xor(s, o);
    __shared__ float red[4];
    if ((t & 63) == 0) red[t >> 6] = s;
    __syncthreads();
    if (t == 0) {
        float tot = red[0] + red[1] + red[2] + red[3];
        if (bid < 1024) u2[bid] = tot + 16384.0f * bq[bid];
        else w[row] = tot;
    }
}

// sum nz fp32 partials (stride 1M), scale, cast to fp16
__global__ __launch_bounds__(256)
void reduce_cast(const float* __restrict__ part, _Float16* __restrict__ outh,
                 int nz, float scale) {
    const int idx = (blockIdx.x * 256 + threadIdx.x) * 4;
    f32x4 s = {};
    for (int z = 0; z < nz; ++z) {
        f32x4 v = *(const f32x4*)(part + (size_t)z * 1048576 + idx);
        s[0] += v[0]; s[1] += v[1]; s[2] += v[2]; s[3] += v[3];
    }
    half4 h;
    h[0] = (_Float16)(s[0] * scale); h[1] = (_Float16)(s[1] * scale);
    h[2] = (_Float16)(s[2] * scale); h[3] = (_Float16)(s[3] * scale);
    *(half4*)(outh + idx) = h;
}

// row-softmax: reduce 4 split-K partials, add rank-1 terms, scale 1/32,
// softmax over 1024 cols; write attn fp32 + attn^T fp16.
__global__ __launch_bounds__(256)
void softmax_rows(const float* __restrict__ part, const float* __restrict__ u2,
                  const float* __restrict__ bq, const float* __restrict__ bk,
                  const float* __restrict__ w,
                  float* __restrict__ P, _Float16* __restrict__ PT) {
    const int a = blockIdx.x;
    const int t = threadIdx.x;
    __shared__ float red[8];
    const size_t off = (size_t)a * 1024 + t * 4;
    f32x4 s = {};
#pragma unroll
    for (int z = 0; z < 4; ++z) {
        f32x4 v = *(const f32x4*)(part + (size_t)z * 1048576 + off);
        s[0] += v[0]; s[1] += v[1]; s[2] += v[2]; s[3] += v[3];
    }
    const float ru = u2[a], rb = bq[a];
    f32x4 bk4 = *(const f32x4*)(bk + t * 4);
    f32x4 w4 = *(const f32x4*)(w + t * 4);
#pragma unroll
    for (int j = 0; j < 4; ++j) s[j] = (s[j] + ru * bk4[j] + rb * w4[j]) * 0.03125f;

    float m = fmaxf(fmaxf(s[0], s[1]), fmaxf(s[2], s[3]));
    for (int o = 32; o; o >>= 1) m = fmaxf(m, __shfl_xor(m, o));
    if ((t & 63) == 0) red[t >> 6] = m;
    __syncthreads();
    m = fmaxf(fmaxf(red[0], red[1]), fmaxf(red[2], red[3]));

    float e0 = expf(s[0] - m), e1 = expf(s[1] - m);
    float e2 = expf(s[2] - m), e3 = expf(s[3] - m);
    float sum = e0 + e1 + e2 + e3;
    for (int o = 32; o; o >>= 1) sum += __shfl_xor(sum, o);
    if ((t & 63) == 0) red[4 + (t >> 6)] = sum;
    __syncthreads();
    sum = red[4] + red[5] + red[6] + red[7];
    const float inv = 1.0f / sum;

    f32x4 o4 = {e0 * inv, e1 * inv, e2 * inv, e3 * inv};
    *(f32x4*)(P + off) = o4;
    const int b = t * 4;
    PT[(size_t)(b + 0) * 1024 + a] = (_Float16)o4[0];
    PT[(size_t)(b + 1) * 1024 + a] = (_Float16)o4[1];
    PT[(size_t)(b + 2) * 1024 + a] = (_Float16)o4[2];
    PT[(size_t)(b + 3) * 1024 + a] = (_Float16)o4[3];
}

// c[j] += sum_{a in block-chunk} attn[a,j]*bv[a]
__global__ __launch_bounds__(256)
void attn_bv(const float* __restrict__ attn, const float* __restrict__ bv,
             float* __restrict__ c) {
    const int j = blockIdx.x * 256 + threadIdx.x;
    const int a0 = blockIdx.y * 64;
    float s = 0.f;
#pragma unroll 4
    for (int k = 0; k < 64; ++k) {
        const int a = a0 + k;
        s += attn[(size_t)a * 1024 + j] * bv[a];
    }
    atomicAdd(c + j, s);
}

extern "C" void kernel_launch(void* const* d_in, const int* in_sizes, int n_in,
                              void* d_out, int out_size, void* d_ws, size_t ws_size,
                              hipStream_t stream) {
    const float* x  = (const float*)d_in[0];
    const float* Wq = (const float*)d_in[1];
    const float* bq = (const float*)d_in[2];
    const float* Wk = (const float*)d_in[3];
    const float* bk = (const float*)d_in[4];
    const float* Wv = (const float*)d_in[5];
    const float* bv = (const float*)d_in[6];
    float* out  = (float*)d_out;                   // [S,D] fp32
    float* attn = out + (size_t)S_ * D_;           // [D,D] fp32

    char* ws = (char*)d_ws;
    float*    part  = (float*)ws;                          // 32MB, reused 4x
    _Float16* x16   = (_Float16*)(ws + 33554432);          // [S,D]   33.5MB
    _Float16* xT16  = (_Float16*)(ws + 67108864);          // [D,S]   33.5MB
    _Float16* wq16  = (_Float16*)(ws + 100663296);         // [D,D]   2MB
    _Float16* wk16  = (_Float16*)(ws + 102760448);
    _Float16* wvT16 = (_Float16*)(ws + 104857600);
    _Float16* G16   = (_Float16*)(ws + 106954752);
    _Float16* U16   = (_Float16*)(ws + 109051904);
    _Float16* PT    = (_Float16*)(ws + 111149056);
    _Float16* MT16  = (_Float16*)(ws + 113246208);
    float*    mvec  = (float*)(ws + 115343360);            // m, u2, w, c (4KB each)
    float*    u2    = mvec + 1024;
    float*    wv    = u2 + 1024;
    float*    cvec  = wv + 1024;

    // zero m + u2 + w + c region (m and c are accumulated via atomics)
    zero_vec<<<16, 256, 0, stream>>>(mvec, 4096);
    // x: fp16 copy, fp16 transpose, column sums
    cast_transpose<1, 1><<<dim3(16, 256), 256, 0, stream>>>(x, x16, xT16, mvec, S_);
    // weights
    cast_f32_f16<<<512, 256, 0, stream>>>(Wq, wq16, D_ * D_ / 8);
    cast_f32_f16<<<512, 256, 0, stream>>>(Wk, wk16, D_ * D_ / 8);
    cast_transpose<0, 0><<<dim3(16, 16), 256, 0, stream>>>(Wv, nullptr, wvT16, nullptr, D_);
    // u2 = Wq m + S bq ; w = Wk m
    u2w_kernel<<<2048, 256, 0, stream>>>(Wq, Wk, bq, mvec, u2, wv);

    // G = xT * xT^T  (M=N=1024, K=16384, split-K 8) -> fp32 partials -> G16
    gemm_abt<<<dim3(8, 8, 8), 256, 0, stream>>>(xT16, xT16, part, nullptr, 0,
                                                16384, 16384, 1024, 2048, 1.0f, 1048576);
    reduce_cast<<<1024, 256, 0, stream>>>(part, G16, 8, 1.0f);
    // U = Wq * G  (G symmetric -> A.B^T form; 1024^3 split-K 4)
    gemm_abt<<<dim3(8, 8, 4), 256, 0, stream>>>(wq16, G16, part, nullptr, 0,
                                                1024, 1024, 1024, 256, 1.0f, 1048576);
    reduce_cast<<<1024, 256, 0, stream>>>(part, U16, 4, 1.0f);
    // scores partials = U * Wk^T
    gemm_abt<<<dim3(8, 8, 4), 256, 0, stream>>>(U16, wk16, part, nullptr, 0,
                                                1024, 1024, 1024, 256, 1.0f, 1048576);
    // softmax (+rank-1 terms, scale 1/32) -> attn fp32 + PT fp16
    softmax_rows<<<1024, 256, 0, stream>>>(part, u2, bq, bk, wv, attn, PT);
    // c = attn^T bv
    attn_bv<<<dim3(4, 16), 256, 0, stream>>>(attn, bv, cvec);
    // MT[j,i] = sum_a attn[a,j] Wv[a,i]  (A=PT, B=WvT)
    gemm_abt<<<dim3(8, 8, 4), 256, 0, stream>>>(PT, wvT16, part, nullptr, 0,
                                                1024, 1024, 1024, 256, 1.0f, 1048576);
    reduce_cast<<<1024, 256, 0, stream>>>(part, MT16, 4, 1.0f);
    // out = x16 * MT^T + c  (M=16384, N=1024, K=1024)
    gemm_abt<<<dim3(8, 128, 1), 256, 0, stream>>>(x16, MT16, out, cvec, 2,
                                                  1024, 1024, 1024, 1024, 1.0f, 0);
}

// Round 3
// 192.322 us; speedup vs baseline: 1.5902x; 1.1767x over previous
//
#include <hip/hip_runtime.h>
#include <hip/hip_bf16.h>
#include <stdint.h>

// BertAttention (feature-axis attention), algebraically restructured:
//   G = x^T x  [D,D];  m = colsum(x);  u2 = Wq m + S*bq;  w = Wk m
//   scores = (Wq G Wk^T + u2 bk^T + bq w^T)/sqrt(D); attn = softmax(scores)
//   out = x (Wv^T attn) + 1 (bv^T attn)
// Big GEMMs (G, out) on a 256x256 8-wave 3-phase counted-vmcnt engine
// (T2 swizzle + T3/T4 + T5); small 1024^3 GEMMs on the proven 128^2 engine.

#define S_ 16384
#define D_ 1024

typedef _Float16 half8 __attribute__((ext_vector_type(8)));
typedef _Float16 half4 __attribute__((ext_vector_type(4)));
typedef float f32x4 __attribute__((ext_vector_type(4)));

__device__ __forceinline__ void gload_lds16(const _Float16* g, _Float16* l) {
    __builtin_amdgcn_global_load_lds(
        (const __attribute__((address_space(1))) void*)g,
        (__attribute__((address_space(3))) void*)l, 16, 0, 0);
}

// ---------------------------------------------------------------- gemm256
// C[m,n] = sum_k A[m,k]*B[n,k] (+ col bias). 256x256 tile, BK=64, 8 waves
// (2M x 4N), double-buffered LDS (128KiB), XOR-swizzled (st-style) LDS,
// 3 phases per K-tile with counted vmcnt(4) (never 0 in loop), setprio
// around MFMA clusters. Split-K via bz with partial stride mn.
#define VM4() asm volatile("s_waitcnt vmcnt(4)" ::: "memory")
#define BARR() do { __builtin_amdgcn_s_barrier(); __builtin_amdgcn_sched_barrier(0); } while (0)
#define LGKM0() do { asm volatile("s_waitcnt lgkmcnt(0)" ::: "memory"); __builtin_amdgcn_sched_barrier(0); } while (0)

#define STAGEA(H, KT, NX) do { \
    const _Float16* _s = srcA + (size_t)((H) * 128) * lda + (size_t)(KT) * 64; \
    _Float16* _d = AsS + (NX) * 16384 + ((H) * 128 + 8 * w) * 64; \
    gload_lds16(_s, _d); \
    gload_lds16(_s + (size_t)64 * lda, _d + 4096); \
} while (0)

#define STAGEB(H, KT, NX) do { \
    const _Float16* _s = srcB + (size_t)((H) * 128) * ldb + (size_t)(KT) * 64; \
    _Float16* _d = BsS + (NX) * 16384 + ((H) * 128 + 8 * w) * 64; \
    gload_lds16(_s, _d); \
    gload_lds16(_s + (size_t)64 * ldb, _d + 4096); \
} while (0)

#define READA(QA) do { _Pragma("unroll") \
    for (int fm = 0; fm < 4; ++fm) { \
        af[fm][0] = *(const half8*)(pA + (((QA) * 64 + fm * 16) << 7) + cx0); \
        af[fm][1] = *(const half8*)(pA + (((QA) * 64 + fm * 16) << 7) + cx1); } \
} while (0)

#define READB(BF, QB) do { _Pragma("unroll") \
    for (int fn = 0; fn < 2; ++fn) { \
        BF[fn][0] = *(const half8*)(pB + (((QB) * 32 + fn * 16) << 7) + cx0); \
        BF[fn][1] = *(const half8*)(pB + (((QB) * 32 + fn * 16) << 7) + cx1); } \
} while (0)

#define MFMAB(QA, QB, BF) do { _Pragma("unroll") \
    for (int fm = 0; fm < 4; ++fm) { _Pragma("unroll") \
        for (int fn = 0; fn < 2; ++fn) { \
            f32x4 _c = acc[(QA) * 4 + fm][(QB) * 2 + fn]; \
            _c = __builtin_amdgcn_mfma_f32_16x16x32_f16(af[fm][0], BF[fn][0], _c, 0, 0, 0); \
            _c = __builtin_amdgcn_mfma_f32_16x16x32_f16(af[fm][1], BF[fn][1], _c, 0, 0, 0); \
            acc[(QA) * 4 + fm][(QB) * 2 + fn] = _c; } } \
} while (0)

template <int F16OUT, int BIAS>
__global__ __launch_bounds__(512, 2)
void gemm256(const _Float16* __restrict__ A, const _Float16* __restrict__ B,
             void* __restrict__ C, const float* __restrict__ bias,
             int lda, int ldb, int ldc, int ksub, long long mn,
             int ntx, int ntxy, int cpx) {
    __shared__ _Float16 As[2][16384];
    __shared__ _Float16 Bs[2][16384];
    const int t = threadIdx.x;
    const int l = t & 63;
    const int w = t >> 6;
    const int wm = w >> 2, wn = w & 3;

    // bijective XCD swizzle (gridDim.x % 8 == 0)
    const int hb = blockIdx.x;
    const int lg = (hb & 7) * cpx + (hb >> 3);
    const int bz = lg / ntxy;
    const int rem = lg - bz * ntxy;
    const int by = rem / ntx;
    const int bx = rem - by * ntx;
    const size_t m0 = (size_t)by * 256;
    const size_t n0 = (size_t)bx * 256;
    const size_t k0 = (size_t)bz * (size_t)ksub;
    const long long coff = (long long)bz * mn;

    // stage source: row = 8w + (l>>3) within 64-row chunk; col pre-swizzled
    // so that linear LDS dest + XOR-read form the same involution.
    const int colsw = 8 * ((l & 7) ^ (l >> 3));
    const _Float16* srcA = A + (m0 + 8 * w + (l >> 3)) * (size_t)lda + k0 + colsw;
    const _Float16* srcB = B + (n0 + 8 * w + (l >> 3)) * (size_t)ldb + k0 + colsw;
    _Float16* AsS = &As[0][0];
    _Float16* BsS = &Bs[0][0];

    // read-side swizzled byte cols for ks=0,1 (row&7 == l&7 for all frags)
    const int cx0 = (((l >> 4) << 4)) ^ ((l & 7) << 4);
    const int cx1 = (64 + ((l >> 4) << 4)) ^ ((l & 7) << 4);
    const char* basePA = (const char*)AsS + (wm * 128 + (l & 15)) * 128;
    const char* basePB = (const char*)BsS + (wn * 64 + (l & 15)) * 128;

    f32x4 acc[8][4] = {};
    half8 af[4][2], bf0[2][2], bf1[2][2];

    const int nk = ksub >> 6;

    // prologue: stage tile 0 into buf 0 in steady-state issue order
    STAGEA(0, 0, 0); STAGEB(0, 0, 0); STAGEB(1, 0, 0); STAGEA(1, 0, 0);

    for (int kt = 0; kt < nk; ++kt) {
        const int p = kt & 1, nx = p ^ 1;
        const int ktn = kt + 1;
        const bool hn = ktn < nk;
        const char* pA = basePA + p * 32768;
        const char* pB = basePB + p * 32768;

        // phase 0: read A0,B0; stage A0(t+1); mfma quadrant (0,0)
        VM4(); BARR();
        READA(0); READB(bf0, 0);
        if (hn) STAGEA(0, ktn, nx);
        LGKM0();
        __builtin_amdgcn_s_setprio(1);
        MFMAB(0, 0, bf0);
        __builtin_amdgcn_s_setprio(0);

        // phase 1: read B1; stage B0(t+1); mfma (0,1)
        VM4(); BARR();
        READB(bf1, 1);
        if (hn) STAGEB(0, ktn, nx);
        LGKM0();
        __builtin_amdgcn_s_setprio(1);
        MFMAB(0, 1, bf1);
        __builtin_amdgcn_s_setprio(0);

        // phase 2: read A1; stage B1,A1(t+1); mfma (1,0),(1,1)
        VM4(); BARR();
        READA(1);
        if (hn) { STAGEB(1, ktn, nx); STAGEA(1, ktn, nx); }
        LGKM0();
        __builtin_amdgcn_s_setprio(1);
        MFMAB(1, 0, bf0);
        MFMAB(1, 1, bf1);
        __builtin_amdgcn_s_setprio(0);
    }

    // epilogue: C/D layout col=lane&15, row=(lane>>4)*4+r
    const int cr = (l >> 4) << 2;
    const int cc = l & 15;
#pragma unroll
    for (int n = 0; n < 4; ++n) {
        const size_t col = n0 + wn * 64 + n * 16 + cc;
        const float bb = BIAS ? bias[col] : 0.f;
#pragma unroll
        for (int m = 0; m < 8; ++m) {
            const size_t row0 = m0 + wm * 128 + m * 16 + cr;
#pragma unroll
            for (int r = 0; r < 4; ++r) {
                const float val = acc[m][n][r] + bb;
                if (F16OUT)
                    ((_Float16*)C)[coff + (long long)(row0 + r) * ldc + col] = (_Float16)val;
                else
                    ((float*)C)[coff + (long long)(row0 + r) * ldc + col] = val;
            }
        }
    }
}

// ------------------------------------------------- 128^2 engine (small GEMMs)
__global__ __launch_bounds__(256, 2)
void gemm_abt(const _Float16* __restrict__ A, const _Float16* __restrict__ B,
              float* __restrict__ C, const float* __restrict__ bias,
              int bias_mode, int lda, int ldb, int ldc, int ksub,
              float scale, long long mn) {
    const int t = threadIdx.x;
    const int lane = t & 63;
    const int wave = t >> 6;
    const int wr = (wave >> 1) * 64;
    const int wc = (wave & 1) * 64;
    const size_t m0 = (size_t)blockIdx.y * 128;
    const size_t n0 = (size_t)blockIdx.x * 128;
    const size_t k0 = (size_t)blockIdx.z * (size_t)ksub;
    const long long coff = (long long)blockIdx.z * mn;

    __shared__ _Float16 As[128 * 32];
    __shared__ _Float16 Bs[128 * 32];

    f32x4 acc[4][4] = {};

    const _Float16* a0 = A + (m0 + (size_t)(t >> 2)) * (size_t)lda + k0 + (t & 3) * 8;
    const _Float16* a1 = a0 + (size_t)64 * lda;
    const _Float16* b0 = B + (n0 + (size_t)(t >> 2)) * (size_t)ldb + k0 + (t & 3) * 8;
    const _Float16* b1 = b0 + (size_t)64 * ldb;
    _Float16* AsW0 = As + wave * 512;
    _Float16* AsW1 = As + 2048 + wave * 512;
    _Float16* BsW0 = Bs + wave * 512;
    _Float16* BsW1 = Bs + 2048 + wave * 512;

    const int nk = ksub >> 5;
    for (int kt = 0; kt < nk; ++kt) {
        __syncthreads();
        gload_lds16(a0, AsW0);
        gload_lds16(a1, AsW1);
        gload_lds16(b0, BsW0);
        gload_lds16(b1, BsW1);
        a0 += 32; a1 += 32; b0 += 32; b1 += 32;
        __syncthreads();

        half8 af[4], bf[4];
#pragma unroll
        for (int i = 0; i < 4; ++i)
            af[i] = *(const half8*)(As + (wr + i * 16 + (lane & 15)) * 32 + (lane >> 4) * 8);
#pragma unroll
        for (int i = 0; i < 4; ++i)
            bf[i] = *(const half8*)(Bs + (wc + i * 16 + (lane & 15)) * 32 + (lane >> 4) * 8);
#pragma unroll
        for (int i = 0; i < 4; ++i)
#pragma unroll
            for (int j = 0; j < 4; ++j)
                acc[i][j] = __builtin_amdgcn_mfma_f32_16x16x32_f16(af[i], bf[j], acc[i][j], 0, 0, 0);
    }

    const int cr = (lane >> 4) * 4;
    const int cc = lane & 15;
#pragma unroll
    for (int i = 0; i < 4; ++i) {
#pragma unroll
        for (int j = 0; j < 4; ++j) {
            const size_t row0 = m0 + wr + i * 16 + cr;
            const size_t col = n0 + wc + j * 16 + cc;
            const float bcol = (bias_mode == 2) ? bias[col] : 0.f;
#pragma unroll
            for (int r = 0; r < 4; ++r) {
                float val = acc[i][j][r] * scale + bcol;
                C[coff + (long long)(row0 + r) * ldc + col] = val;
            }
        }
    }
}

// ------------------------------------------------------------- prep kernels
__global__ void cast_f32_f16(const float* __restrict__ in, _Float16* __restrict__ out, int n8) {
    int i = blockIdx.x * 256 + threadIdx.x;
    if (i >= n8) return;
    const f32x4* p = (const f32x4*)in + (size_t)i * 2;
    f32x4 x0 = p[0], x1 = p[1];
    half8 h;
    h[0] = (_Float16)x0[0]; h[1] = (_Float16)x0[1];
    h[2] = (_Float16)x0[2]; h[3] = (_Float16)x0[3];
    h[4] = (_Float16)x1[0]; h[5] = (_Float16)x1[1];
    h[6] = (_Float16)x1[2]; h[7] = (_Float16)x1[3];
    ((half8*)out)[i] = h;
}

template <int WRITE_ROW, int COLSUM>
__global__ __launch_bounds__(256)
void cast_transpose(const float* __restrict__ in, _Float16* __restrict__ outRow,
                    _Float16* __restrict__ outT, float* __restrict__ msum, int ldT) {
    __shared__ _Float16 tile[64][66];
    __shared__ float red[16][16][4];
    const int t = threadIdx.x;
    const int c0 = blockIdx.x * 64;
    const int r0 = blockIdx.y * 64;
    const int cg = t & 15;
    const int rb = t >> 4;
    f32x4 csum = {};
#pragma unroll
    for (int it = 0; it < 4; ++it) {
        const int rr = rb + it * 16;
        f32x4 v = *(const f32x4*)(in + (size_t)(r0 + rr) * 1024 + c0 + cg * 4);
        if (COLSUM) { csum[0] += v[0]; csum[1] += v[1]; csum[2] += v[2]; csum[3] += v[3]; }
        _Float16 h0 = (_Float16)v[0], h1 = (_Float16)v[1];
        _Float16 h2 = (_Float16)v[2], h3 = (_Float16)v[3];
        tile[rr][cg * 4 + 0] = h0; tile[rr][cg * 4 + 1] = h1;
        tile[rr][cg * 4 + 2] = h2; tile[rr][cg * 4 + 3] = h3;
        if (WRITE_ROW) {
            half4 h = {h0, h1, h2, h3};
            *(half4*)(outRow + (size_t)(r0 + rr) * 1024 + c0 + cg * 4) = h;
        }
    }
    if (COLSUM) {
        red[rb][cg][0] = csum[0]; red[rb][cg][1] = csum[1];
        red[rb][cg][2] = csum[2]; red[rb][cg][3] = csum[3];
    }
    __syncthreads();
    if (COLSUM && t < 64) {
        float s = 0.f;
#pragma unroll
        for (int k = 0; k < 16; ++k) s += red[k][t >> 2][t & 3];
        atomicAdd(msum + c0 + t, s);
    }
    const int i = t >> 2, ch = (t & 3) * 16;
    half8 h0v, h1v;
#pragma unroll
    for (int j = 0; j < 8; ++j) h0v[j] = tile[ch + j][i];
#pragma unroll
    for (int j = 0; j < 8; ++j) h1v[j] = tile[ch + 8 + j][i];
    *(half8*)(outT + (size_t)(c0 + i) * ldT + r0 + ch) = h0v;
    *(half8*)(outT + (size_t)(c0 + i) * ldT + r0 + ch + 8) = h1v;
}

__global__ void zero_vec(float* __restrict__ p, int n) {
    int i = blockIdx.x * 256 + threadIdx.x;
    if (i < n) p[i] = 0.f;
}

__global__ __launch_bounds__(256)
void u2w_kernel(const float* __restrict__ Wq, const float* __restrict__ Wk,
                const float* __restrict__ bq, const float* __restrict__ m,
                float* __restrict__ u2, float* __restrict__ w) {
    const int bid = blockIdx.x;
    const int t = threadIdx.x;
    const float* W = (bid < 1024) ? Wq : Wk;
    const int row = (bid < 1024) ? bid : bid - 1024;
    float s = 0.f;
#pragma unroll
    for (int it = 0; it < 4; ++it) {
        const int i = t + it * 256;
        s += W[(size_t)row * 1024 + i] * m[i];
    }
    for (int o = 32; o; o >>= 1) s += __shfl_xor(s, o);
    __shared__ float red[4];
    if ((t & 63) == 0) red[t >> 6] = s;
    __syncthreads();
    if (t == 0) {
        float tot = red[0] + red[1] + red[2] + red[3];
        if (bid < 1024) u2[bid] = tot + 16384.0f * bq[bid];
        else w[row] = tot;
    }
}

// reduce 16 f16 split-K partial slices -> f16 (fp32 accumulate)
__global__ __launch_bounds__(256)
void reduce_g(const _Float16* __restrict__ part, _Float16* __restrict__ G16) {
    const size_t off = ((size_t)blockIdx.x * 256 + threadIdx.x) * 8;
    float s[8] = {};
    for (int z = 0; z < 16; ++z) {
        half8 v = *(const half8*)(part + (size_t)z * 1048576 + off);
#pragma unroll
        for (int j = 0; j < 8; ++j) s[j] += (float)v[j];
    }
    half8 o;
#pragma unroll
    for (int j = 0; j < 8; ++j) o[j] = (_Float16)s[j];
    *(half8*)(G16 + off) = o;
}

// reduce nz fp32 slices, scale, cast f16
__global__ __launch_bounds__(256)
void reduce_cast(const float* __restrict__ part, _Float16* __restrict__ outh,
                 int nz, float scale) {
    const int idx = (blockIdx.x * 256 + threadIdx.x) * 4;
    f32x4 s = {};
    for (int z = 0; z < nz; ++z) {
        f32x4 v = *(const f32x4*)(part + (size_t)z * 1048576 + idx);
        s[0] += v[0]; s[1] += v[1]; s[2] += v[2]; s[3] += v[3];
    }
    half4 h;
    h[0] = (_Float16)(s[0] * scale); h[1] = (_Float16)(s[1] * scale);
    h[2] = (_Float16)(s[2] * scale); h[3] = (_Float16)(s[3] * scale);
    *(half4*)(outh + idx) = h;
}

__global__ __launch_bounds__(256)
void softmax_rows(const float* __restrict__ part, const float* __restrict__ u2,
                  const float* __restrict__ bq, const float* __restrict__ bk,
                  const float* __restrict__ w,
                  float* __restrict__ P, _Float16* __restrict__ PT) {
    const int a = blockIdx.x;
    const int t = threadIdx.x;
    __shared__ float red[8];
    const size_t off = (size_t)a * 1024 + t * 4;
    f32x4 s = {};
#pragma unroll
    for (int z = 0; z < 4; ++z) {
        f32x4 v = *(const f32x4*)(part + (size_t)z * 1048576 + off);
        s[0] += v[0]; s[1] += v[1]; s[2] += v[2]; s[3] += v[3];
    }
    const float ru = u2[a], rb = bq[a];
    f32x4 bk4 = *(const f32x4*)(bk + t * 4);
    f32x4 w4 = *(const f32x4*)(w + t * 4);
#pragma unroll
    for (int j = 0; j < 4; ++j) s[j] = (s[j] + ru * bk4[j] + rb * w4[j]) * 0.03125f;

    float m = fmaxf(fmaxf(s[0], s[1]), fmaxf(s[2], s[3]));
    for (int o = 32; o; o >>= 1) m = fmaxf(m, __shfl_xor(m, o));
    if ((t & 63) == 0) red[t >> 6] = m;
    __syncthreads();
    m = fmaxf(fmaxf(red[0], red[1]), fmaxf(red[2], red[3]));

    float e0 = expf(s[0] - m), e1 = expf(s[1] - m);
    float e2 = expf(s[2] - m), e3 = expf(s[3] - m);
    float sum = e0 + e1 + e2 + e3;
    for (int o = 32; o; o >>= 1) sum += __shfl_xor(sum, o);
    if ((t & 63) == 0) red[4 + (t >> 6)] = sum;
    __syncthreads();
    sum = red[4] + red[5] + red[6] + red[7];
    const float inv = 1.0f / sum;

    f32x4 o4 = {e0 * inv, e1 * inv, e2 * inv, e3 * inv};
    *(f32x4*)(P + off) = o4;
    const int b = t * 4;
    PT[(size_t)(b + 0) * 1024 + a] = (_Float16)o4[0];
    PT[(size_t)(b + 1) * 1024 + a] = (_Float16)o4[1];
    PT[(size_t)(b + 2) * 1024 + a] = (_Float16)o4[2];
    PT[(size_t)(b + 3) * 1024 + a] = (_Float16)o4[3];
}

__global__ __launch_bounds__(256)
void attn_bv(const float* __restrict__ attn, const float* __restrict__ bv,
             float* __restrict__ c) {
    const int j = blockIdx.x * 256 + threadIdx.x;
    const int a0 = blockIdx.y * 64;
    float s = 0.f;
#pragma unroll 4
    for (int k = 0; k < 64; ++k) {
        const int a = a0 + k;
        s += attn[(size_t)a * 1024 + j] * bv[a];
    }
    atomicAdd(c + j, s);
}

extern "C" void kernel_launch(void* const* d_in, const int* in_sizes, int n_in,
                              void* d_out, int out_size, void* d_ws, size_t ws_size,
                              hipStream_t stream) {
    const float* x  = (const float*)d_in[0];
    const float* Wq = (const float*)d_in[1];
    const float* bq = (const float*)d_in[2];
    const float* Wk = (const float*)d_in[3];
    const float* bk = (const float*)d_in[4];
    const float* Wv = (const float*)d_in[5];
    const float* bv = (const float*)d_in[6];
    float* out  = (float*)d_out;                   // [S,D] fp32
    float* attn = out + (size_t)S_ * D_;           // [D,D] fp32

    char* ws = (char*)d_ws;
    float*    part  = (float*)ws;                          // 32MB, reused
    _Float16* partH = (_Float16*)ws;                       // alias: G f16 partials
    _Float16* x16   = (_Float16*)(ws + 33554432);          // [S,D]   33.5MB
    _Float16* xT16  = (_Float16*)(ws + 67108864);          // [D,S]   33.5MB
    _Float16* wq16  = (_Float16*)(ws + 100663296);         // [D,D]   2MB
    _Float16* wk16  = (_Float16*)(ws + 102760448);
    _Float16* wvT16 = (_Float16*)(ws + 104857600);
    _Float16* G16   = (_Float16*)(ws + 106954752);
    _Float16* U16   = (_Float16*)(ws + 109051904);
    _Float16* PT    = (_Float16*)(ws + 111149056);
    _Float16* MT16  = (_Float16*)(ws + 113246208);
    float*    mvec  = (float*)(ws + 115343360);            // m, u2, w, c
    float*    u2    = mvec + 1024;
    float*    wv    = u2 + 1024;
    float*    cvec  = wv + 1024;

    zero_vec<<<16, 256, 0, stream>>>(mvec, 4096);
    cast_transpose<1, 1><<<dim3(16, 256), 256, 0, stream>>>(x, x16, xT16, mvec, S_);
    cast_f32_f16<<<512, 256, 0, stream>>>(Wq, wq16, D_ * D_ / 8);
    cast_f32_f16<<<512, 256, 0, stream>>>(Wk, wk16, D_ * D_ / 8);
    cast_transpose<0, 0><<<dim3(16, 16), 256, 0, stream>>>(Wv, nullptr, wvT16, nullptr, D_);
    u2w_kernel<<<2048, 256, 0, stream>>>(Wq, Wk, bq, mvec, u2, wv);

    // G = xT * xT^T  (M=N=1024, K=16384, split-K 16, f16 partials)
    gemm256<1, 0><<<256, 512, 0, stream>>>(xT16, xT16, (void*)partH, nullptr,
                                           16384, 16384, 1024, 1024, 1048576LL,
                                           4, 16, 32);
    reduce_g<<<512, 256, 0, stream>>>(partH, G16);
    // U = Wq * G  (G symmetric; 1024^3 split-K 4)
    gemm_abt<<<dim3(8, 8, 4), 256, 0, stream>>>(wq16, G16, part, nullptr, 0,
                                                1024, 1024, 1024, 256, 1.0f, 1048576);
    reduce_cast<<<1024, 256, 0, stream>>>(part, U16, 4, 1.0f);
    // scores partials = U * Wk^T
    gemm_abt<<<dim3(8, 8, 4), 256, 0, stream>>>(U16, wk16, part, nullptr, 0,
                                                1024, 1024, 1024, 256, 1.0f, 1048576);
    softmax_rows<<<1024, 256, 0, stream>>>(part, u2, bq, bk, wv, attn, PT);
    attn_bv<<<dim3(4, 16), 256, 0, stream>>>(attn, bv, cvec);
    // MT[j,i] = sum_a attn[a,j] Wv[a,i]
    gemm_abt<<<dim3(8, 8, 4), 256, 0, stream>>>(PT, wvT16, part, nullptr, 0,
                                                1024, 1024, 1024, 256, 1.0f, 1048576);
    reduce_cast<<<1024, 256, 0, stream>>>(part, MT16, 4, 1.0f);
    // out = x16 * MT^T + cvec  (M=16384, N=1024, K=1024)
    gemm256<0, 1><<<256, 512, 0, stream>>>(x16, MT16, (void*)out, cvec,
                                           1024, 1024, 1024, 1024, 0LL,
                                           4, 256, 32);
}